// Round 5
// baseline (91.298 us; speedup 1.0000x reference)
//
#include <hip/hip_runtime.h>
#include <math.h>

#define BS   16
#define NQ   128
#define NCLS 3
#define T    480
#define P    72
#define BN   (BS * NQ)      // 2048
#define TROW (5 + 2 * P)    // 149
#define TT   32             // targets per t-tile
#define NTT  (T / TT)       // 15
#define BNT  128            // bn per bn-tile
#define NBNT (BN / BNT)     // 16
#define NTHR 512            // 8 waves -> VGPR cap 256, NO spill (1024 capped at 64
                            // and spilled both phases: rounds 1/3, VGPR_Count 36/44)
#define WPB  (NTHR / 64)    // 8 waves

// Single standard kernel, 2D-tiled (16 bn-tiles x 15 t-tiles = 240 blocks).
//  A: per[t] for ALL targets via ballot/popcount  -> per_min is block-local
//     (proven round 3)
//  B: fp64 moments for this block's 32 targets, lane-parallel 5-accumulator
//     body (proven round 4) -> LDS
//  C: 128 bn x 32 t cost from LDS; math byte-identical to round-0 cost kernel.
// Removes one launch + the inter-kernel gap (~20 us controllable slice in the
// two-kernel layout per rounds 3/4 calibration).
__global__ __launch_bounds__(NTHR) void fused(
    const float* __restrict__ logits,
    const float* __restrict__ curves,
    const float* __restrict__ targets,
    float* __restrict__ out)
{
    __shared__ float  sPER[T];        // 1920 B
    __shared__ double sMD[16 * TT];   // 4096 B
    __shared__ float  sEF[5 * TT];    // 640 B : ly,uy,lx,ux,id
    __shared__ float  swm[WPB];

    const int tid  = threadIdx.x;
    const int lane = tid & 63;
    const int wid  = tid >> 6;
    const int bn0  = blockIdx.x * BNT;
    const int t0   = blockIdx.y * TT;

    // ---- phase A: per[t] for ALL targets (ballot/popcount, coalesced) ----
    for (int t = wid; t < T; t += WPB) {
        const float* xs = targets + (size_t)t * TROW + 5;
        bool v0 = (xs[lane] >= 0.0f);                           // p < 64
        bool v1 = (lane < 8) ? (xs[64 + lane] >= 0.0f) : false; // p = 64..71
        int cnt = __popcll(__ballot(v0)) + __popcll(__ballot(v1));
        if (lane == 0) sPER[t] = (float)cnt;
    }

    // ---- phase B: moments for this block's TT targets (lane-parallel) ----
    // wave wid handles tl = wid + 8*rep; lane = (psub, mg).
    const int mg   = lane & 3;        // moment group 0..3
    const int psub = lane >> 2;       // point slot 0..15
#pragma unroll
    for (int rep = 0; rep < TT / WPB; ++rep) {
        const int tl = wid + rep * WPB;
        const float* row = targets + (size_t)(t0 + tl) * TROW;
        const float ly = row[1], uy = row[2], lx = row[3], ux = row[4];
        const float dx = ux - lx, dy = uy - ly;
        const float nrm = sqrtf(dx * dx + dy * dy);

        double a0 = 0.0, a1 = 0.0, a2 = 0.0, a3 = 0.0, e = 0.0;
#pragma unroll
        for (int k = 0; k < 5; ++k) {
            const int p = psub + 16 * k;       // 16 points/iter
            if (p < P) {
                float tx = row[5 + p];
                float ty = row[5 + P + p];
                if (tx >= 0.0f) {
                    float lamf = dx * (tx - lx) + dy * (ty - ly);
                    lamf = lamf / nrm / nrm;   // match reference: dot/nrm/nrm
                    double L  = (double)lamf;
                    double L2 = L * L;         // same association as lp chain
                    double L3 = L2 * L;
                    double txd = (double)tx, tyd = (double)ty;
                    double base = (mg == 0) ? 1.0 : (mg == 1) ? L3
                                : (mg == 2) ? txd : tyd;
                    double esel = (mg == 1) ? (txd * txd + tyd * tyd) : 0.0;
                    a0 += base;
                    a1 += base * L;
                    a2 += base * L2;
                    a3 += base * L3;
                    e  += esel;
                }
            }
        }
        // reduce across the 16 psub slots (xor butterfly, strides 4..32)
#pragma unroll
        for (int off = 4; off <= 32; off <<= 1) {
            a0 += __shfl_xor(a0, off);
            a1 += __shfl_xor(a1, off);
            a2 += __shfl_xor(a2, off);
            a3 += __shfl_xor(a3, off);
            e  += __shfl_xor(e,  off);
        }
        if (psub == 0) {              // lanes 0..3, one per moment group
            if (mg == 0) {            // m0..m3
                sMD[0 * TT + tl] = a0;  sMD[1 * TT + tl] = a1;
                sMD[2 * TT + tl] = a2;  sMD[3 * TT + tl] = a3;
            } else if (mg == 1) {     // m4..m6 = L^3 * L^{1,2,3}, Q
                sMD[4 * TT + tl] = a1;  sMD[5 * TT + tl] = a2;
                sMD[6 * TT + tl] = a3;  sMD[15 * TT + tl] = e;
            } else if (mg == 2) {     // sx_k
                sMD[7 * TT + tl]  = -2.0 * a0;  sMD[8 * TT + tl]  = -2.0 * a1;
                sMD[9 * TT + tl]  = -2.0 * a2;  sMD[10 * TT + tl] = -2.0 * a3;
            } else {                  // sy_k + header
                sMD[11 * TT + tl] = -2.0 * a0;  sMD[12 * TT + tl] = -2.0 * a1;
                sMD[13 * TT + tl] = -2.0 * a2;  sMD[14 * TT + tl] = -2.0 * a3;
                sEF[0 * TT + tl] = ly;
                sEF[1 * TT + tl] = uy;
                sEF[2 * TT + tl] = lx;
                sEF[3 * TT + tl] = ux;
                sEF[4 * TT + tl] = row[0];   // class id
            }
        }
    }
    __syncthreads();

    // ---- per_min over all 480 (block-local) ------------------------------
    float pm = (tid < T) ? sPER[tid] : 1e30f;
#pragma unroll
    for (int off = 32; off > 0; off >>= 1) pm = fminf(pm, __shfl_xor(pm, off));
    if (lane == 0) swm[wid] = pm;
    __syncthreads();
    float per_min = swm[0];
#pragma unroll
    for (int i = 1; i < WPB; ++i) per_min = fminf(per_min, swm[i]);

    // ---- phase C: cost for BNT bn x TT t (round-0 math, unchanged) -------
    const int tl  = tid & (TT - 1);   // 0..31
    const int bnl = tid >> 5;         // 0..15
    const int t   = t0 + tl;

    double m[16];
#pragma unroll
    for (int r = 0; r < 16; ++r) m[r] = sMD[r * TT + tl];  // 8B stride: free

    const float ly = sEF[0 * TT + tl], uy = sEF[1 * TT + tl];
    const float lx = sEF[2 * TT + tl], ux = sEF[3 * TT + tl];
    const int   id = (int)sEF[4 * TT + tl];
    const float w  = sqrtf(per_min / sPER[t]);

#pragma unroll
    for (int j = 0; j < BNT / 16; ++j) {
        const int bn = bn0 + j * 16 + bnl;
        const float* ob = curves + (size_t)bn * 8;         // 2 bn/wave
        float o0 = ob[0], o1 = ob[1], o2 = ob[2], o3 = ob[3];
        float o4 = ob[4], o5 = ob[5], o6 = ob[6], o7 = ob[7];
        float a0 = o2, a1 = o3 - o4 - o5 - o2, a2 = o5, a3 = o4;
        float b0 = o0, b1 = o1 - o6 - o7 - o0, b2 = o7, b3 = o6;

        double A0 = a0, A1 = a1, A2 = a2, A3 = a3;
        double B0 = b0, B1 = b1, B2 = b2, B3 = b3;
        double acc = m[15]
            + (A0 * A0 + B0 * B0) * m[0]
            + 2.0 * (A0 * A1 + B0 * B1) * m[1]
            + (2.0 * (A0 * A2 + B0 * B2) + A1 * A1 + B1 * B1) * m[2]
            + 2.0 * (A0 * A3 + A1 * A2 + B0 * B3 + B1 * B2) * m[3]
            + (2.0 * (A1 * A3 + B1 * B3) + A2 * A2 + B2 * B2) * m[4]
            + 2.0 * (A2 * A3 + B2 * B3) * m[5]
            + (A3 * A3 + B3 * B3) * m[6]
            + A0 * m[7]  + A1 * m[8]  + A2 * m[9]  + A3 * m[10]
            + B0 * m[11] + B1 * m[12] + B2 * m[13] + B3 * m[14];

        const float* lg = logits + (size_t)bn * NCLS;      // 2 bn/wave
        float l0 = lg[0], l1 = lg[1], l2 = lg[2];
        float mx = fmaxf(l0, fmaxf(l1, l2));
        float e0 = __expf(l0 - mx), e1 = __expf(l1 - mx), e2 = __expf(l2 - mx);
        float inv = 1.0f / (e0 + e1 + e2);
        float prob = (id == 0) ? e0 * inv : ((id == 1) ? e1 * inv : e2 * inv);

        float cp = (float)acc * w * 0.1f;
        float cl = 0.5f * (fabsf(b0 - ly) + fabsf(a0 - lx));
        float cu = 0.5f * (fabsf(o1 - uy) + fabsf(o3 - ux));
        out[(size_t)bn * T + t] = -prob + cp + cl + cu;    // 128B segments
    }
}

extern "C" void kernel_launch(void* const* d_in, const int* in_sizes, int n_in,
                              void* d_out, int out_size, void* d_ws, size_t ws_size,
                              hipStream_t stream) {
    const float* logits  = (const float*)d_in[0];  // (16,128,3)
    const float* curves  = (const float*)d_in[1];  // (16,128,8)
    const float* targets = (const float*)d_in[2];  // (480,149)
    (void)d_ws; (void)ws_size;

    fused<<<dim3(NBNT, NTT), NTHR, 0, stream>>>(logits, curves, targets,
                                                (float*)d_out);
}

// Round 6
// 66.957 us; speedup vs baseline: 1.3635x; 1.3635x over previous
//
#include <hip/hip_runtime.h>
#include <math.h>

#define BS   16
#define NQ   128
#define NCLS 3
#define T    480
#define P    72
#define BN   (BS * NQ)      // 2048
#define TROW (5 + 2 * P)    // 149
#define BNB  4              // bn per block in cost kernel

// ws layout (bytes):
//   MD  double[16][T] @ 0      (61440)
//     rows 0..6  : m_j  = sum_valid lam^j            (j=0..6)
//     rows 7..10 : sx_k = -2 * sum_valid tx*lam^k    (k=0..3)
//     rows 11..14: sy_k = -2 * sum_valid ty*lam^k    (k=0..3)
//     row  15    : Q    = sum_valid (tx^2 + ty^2)
//   EF  float[6][T]   @ 61440  (11520): ly, uy, lx, ux, per, id
// (round-1 proved the 256 MiB ws poison fill runs unconditionally -> ws free;
//  rounds 3/5 proved monoliths die on per[t] re-scan redundancy; round 2
//  proved cooperative grid.sync costs ~40 us. Two-kernel is the structure.)
#define MD_OFF_B 0
#define EF_OFF_B 61440

// UNCHANGED from round 4 (proven). One wave per target, lane-parallel moment
// groups: lane = (psub, mg); each lane keeps 5 fp64 accumulators.
__global__ __launch_bounds__(64) void moments_kernel(const float* __restrict__ targets,
                                                     double* __restrict__ MD,
                                                     float* __restrict__ EF) {
    const int t    = blockIdx.x;
    const int lane = threadIdx.x;
    const int mg   = lane & 3;        // moment group 0..3
    const int psub = lane >> 2;       // point slot 0..15

    const float* row = targets + (size_t)t * TROW;
    const float ly = row[1], uy = row[2], lx = row[3], ux = row[4];
    const float dx = ux - lx, dy = uy - ly;
    const float nrm = sqrtf(dx * dx + dy * dy);

    double a0 = 0.0, a1 = 0.0, a2 = 0.0, a3 = 0.0, e = 0.0;

#pragma unroll
    for (int k = 0; k < 5; ++k) {
        const int p = psub + 16 * k;           // 16 points/iter, 4-lane broadcast
        if (p < P) {
            float tx = row[5 + p];
            float ty = row[5 + P + p];
            if (tx >= 0.0f) {
                float lamf = dx * (tx - lx) + dy * (ty - ly);
                lamf = lamf / nrm / nrm;       // match reference: dot/nrm/nrm
                double L  = (double)lamf;
                double L2 = L * L;             // same association as lp chain
                double L3 = L2 * L;
                double txd = (double)tx, tyd = (double)ty;
                double base = (mg == 0) ? 1.0 : (mg == 1) ? L3
                            : (mg == 2) ? txd : tyd;
                double esel = (mg == 0) ? 1.0
                            : (mg == 1) ? (txd * txd + tyd * tyd) : 0.0;
                a0 += base;
                a1 += base * L;
                a2 += base * L2;
                a3 += base * L3;
                e  += esel;
            }
        }
    }

#pragma unroll
    for (int off = 4; off <= 32; off <<= 1) {
        a0 += __shfl_xor(a0, off);
        a1 += __shfl_xor(a1, off);
        a2 += __shfl_xor(a2, off);
        a3 += __shfl_xor(a3, off);
        e  += __shfl_xor(e,  off);
    }

    if (psub == 0) {                  // lanes 0..3, one per moment group
        if (mg == 0) {                // m0..m3, per-count
            MD[0 * T + t] = a0;  MD[1 * T + t] = a1;
            MD[2 * T + t] = a2;  MD[3 * T + t] = a3;
            EF[4 * T + t] = (float)e;
        } else if (mg == 1) {         // m4..m6 = L^3 * L^{1,2,3}, Q
            MD[4 * T + t] = a1;  MD[5 * T + t] = a2;  MD[6 * T + t] = a3;
            MD[15 * T + t] = e;
        } else if (mg == 2) {         // sx_k
            MD[7 * T + t]  = -2.0 * a0;  MD[8 * T + t]  = -2.0 * a1;
            MD[9 * T + t]  = -2.0 * a2;  MD[10 * T + t] = -2.0 * a3;
        } else {                      // sy_k + header
            MD[11 * T + t] = -2.0 * a0;  MD[12 * T + t] = -2.0 * a1;
            MD[13 * T + t] = -2.0 * a2;  MD[14 * T + t] = -2.0 * a3;
            EF[0 * T + t] = ly;
            EF[1 * T + t] = uy;
            EF[2 * T + t] = lx;
            EF[3 * T + t] = ux;
            EF[5 * T + t] = row[0];   // class id
        }
    }
}

// Cost kernel with block-uniform work hoisted to LDS:
//  - lanes 0..3 (wave 0): fp64 coeffs c0..c14 for bn0..bn0+3 (straight-line)
//  - lanes 64..67 (wave 1): softmax probs (3) + aux {o0,o2,o1,o3} in f32
// Inner loop per (t, bn): 15 broadcast ds_read_b64 + 15 v_fma_f64 + f32 tail,
// replacing ~38 redundant per-thread fp64 VALU ops per iteration.
__global__ __launch_bounds__(512) void cost_kernel(const float* __restrict__ logits,
                                                   const float* __restrict__ curves,
                                                   const double* __restrict__ MD,
                                                   const float* __restrict__ EF,
                                                   float* __restrict__ out) {
    __shared__ double sC[BNB][15];    // 480 B : quadform coeffs
    __shared__ float  sProb[BNB][4];  // 64 B  : softmax prob per class (+pad)
    __shared__ float  sAux[BNB][4];   // 64 B  : o0, o2, o1, o3
    __shared__ float  wavemin[8];

    const int t    = threadIdx.x;
    const int bn0  = blockIdx.x * BNB;
    const int lane = t & 63;
    const int wid  = t >> 6;

    // ---- hoist: fp64 coeffs (wave 0, lanes 0..3), one bn per lane --------
    if (wid == 0 && lane < BNB) {
        const float* ob = curves + (size_t)(bn0 + lane) * 8;
        float o0 = ob[0], o1 = ob[1], o2 = ob[2], o3 = ob[3];
        float o4 = ob[4], o5 = ob[5], o6 = ob[6], o7 = ob[7];
        float a0 = o2, a1 = o3 - o4 - o5 - o2, a2 = o5, a3 = o4;
        float b0 = o0, b1 = o1 - o6 - o7 - o0, b2 = o7, b3 = o6;
        double A0 = a0, A1 = a1, A2 = a2, A3 = a3;
        double B0 = b0, B1 = b1, B2 = b2, B3 = b3;
        sC[lane][0]  = A0 * A0 + B0 * B0;                          // *m0
        sC[lane][1]  = 2.0 * (A0 * A1 + B0 * B1);                  // *m1
        sC[lane][2]  = 2.0 * (A0 * A2 + B0 * B2) + A1 * A1 + B1 * B1;
        sC[lane][3]  = 2.0 * (A0 * A3 + A1 * A2 + B0 * B3 + B1 * B2);
        sC[lane][4]  = 2.0 * (A1 * A3 + B1 * B3) + A2 * A2 + B2 * B2;
        sC[lane][5]  = 2.0 * (A2 * A3 + B2 * B3);
        sC[lane][6]  = A3 * A3 + B3 * B3;
        sC[lane][7]  = A0;  sC[lane][8]  = A1;                     // *m7..m10
        sC[lane][9]  = A2;  sC[lane][10] = A3;
        sC[lane][11] = B0;  sC[lane][12] = B1;                     // *m11..m14
        sC[lane][13] = B2;  sC[lane][14] = B3;
    }
    // ---- hoist: probs + aux (wave 1, lanes 0..3) --------------------------
    if (wid == 1 && lane < BNB) {
        const float* lg = logits + (size_t)(bn0 + lane) * NCLS;
        float l0 = lg[0], l1 = lg[1], l2 = lg[2];
        float mx = fmaxf(l0, fmaxf(l1, l2));
        float e0 = __expf(l0 - mx), e1 = __expf(l1 - mx), e2 = __expf(l2 - mx);
        float inv = 1.0f / (e0 + e1 + e2);
        sProb[lane][0] = e0 * inv;
        sProb[lane][1] = e1 * inv;
        sProb[lane][2] = e2 * inv;
        const float* ob = curves + (size_t)(bn0 + lane) * 8;
        sAux[lane][0] = ob[0];   // b0 (o0) for cost_lower
        sAux[lane][1] = ob[2];   // a0 (o2) for cost_lower
        sAux[lane][2] = ob[1];   // o1 for cost_upper
        sAux[lane][3] = ob[3];   // o3 for cost_upper
    }

    // ---- per_min across all 480 t (block covers all t -> global) ---------
    float per = (t < T) ? EF[4 * T + t] : 1e30f;
    float pm = per;
#pragma unroll
    for (int off = 32; off > 0; off >>= 1) pm = fminf(pm, __shfl_xor(pm, off));
    if (lane == 0) wavemin[wid] = pm;
    __syncthreads();                  // also publishes sC/sProb/sAux
    float per_min = wavemin[0];
#pragma unroll
    for (int i = 1; i < 8; ++i) per_min = fminf(per_min, wavemin[i]);

    if (t >= T) return;
    const float w = sqrtf(per_min / per);

    double m[16];
#pragma unroll
    for (int r = 0; r < 16; ++r) m[r] = MD[r * T + t];   // coalesced
    const float ly = EF[0 * T + t], uy = EF[1 * T + t];
    const float lx = EF[2 * T + t], ux = EF[3 * T + t];
    const int   id = (int)EF[5 * T + t];

#pragma unroll
    for (int j = 0; j < BNB; ++j) {
        // 15-term fp64 dot, broadcast LDS reads (uniform addr -> no conflict)
        double acc = m[15];
        double s0 = sC[j][0]  * m[0]  + sC[j][1]  * m[1];
        double s1 = sC[j][2]  * m[2]  + sC[j][3]  * m[3];
        double s2 = sC[j][4]  * m[4]  + sC[j][5]  * m[5];
        double s3 = sC[j][6]  * m[6]  + sC[j][7]  * m[7];
        double s4 = sC[j][8]  * m[8]  + sC[j][9]  * m[9];
        double s5 = sC[j][10] * m[10] + sC[j][11] * m[11];
        double s6 = sC[j][12] * m[12] + sC[j][13] * m[13];
        double s7 = sC[j][14] * m[14];
        acc += ((s0 + s1) + (s2 + s3)) + ((s4 + s5) + (s6 + s7));

        const float prob = sProb[j][id];
        const float b0 = sAux[j][0], a0 = sAux[j][1];
        const float o1 = sAux[j][2], o3 = sAux[j][3];

        float cp = (float)acc * w * 0.1f;
        float cl = 0.5f * (fabsf(b0 - ly) + fabsf(a0 - lx));   // |ob0-ly|+|ob2-lx|
        float cu = 0.5f * (fabsf(o1 - uy) + fabsf(o3 - ux));   // |ob1-uy|+|ob3-ux|
        out[(size_t)(bn0 + j) * T + t] = -prob + cp + cl + cu; // coalesced
    }
}

extern "C" void kernel_launch(void* const* d_in, const int* in_sizes, int n_in,
                              void* d_out, int out_size, void* d_ws, size_t ws_size,
                              hipStream_t stream) {
    const float* logits  = (const float*)d_in[0];  // (16,128,3)
    const float* curves  = (const float*)d_in[1];  // (16,128,8)
    const float* targets = (const float*)d_in[2];  // (480,149)
    float* out = (float*)d_out;
    char*  ws  = (char*)d_ws;

    double* MD = (double*)(ws + MD_OFF_B);
    float*  EF = (float*) (ws + EF_OFF_B);

    moments_kernel<<<T, 64, 0, stream>>>(targets, MD, EF);
    cost_kernel<<<BN / BNB, 512, 0, stream>>>(logits, curves, MD, EF, out);
}